// Round 12
// baseline (439.744 us; speedup 1.0000x reference)
//
#include <hip/hip_runtime.h>

// Problem constants (reference: S=Q=4096, E=D=2048, all fp32 in/out)
#define S_SEQ 4096
#define Q_SEQ 4096
#define E_DIM 2048
#define D_DIM 2048

typedef __bf16 bf16;
typedef __bf16 bf16x4 __attribute__((ext_vector_type(4)));
typedef __bf16 bf16x8 __attribute__((ext_vector_type(8)));
typedef float f32x4 __attribute__((ext_vector_type(4)));

// ---------------------------------------------------------------------------
// merged cast: 6 segments fp32 -> bf16 (original grid, best-measured config)
// ---------------------------------------------------------------------------
__global__ __launch_bounds__(256) void cast6(
    const float* __restrict__ i0, const float* __restrict__ i1,
    const float* __restrict__ i2, const float* __restrict__ i3,
    const float* __restrict__ i4, const float* __restrict__ i5,
    bf16* __restrict__ o0, bf16* __restrict__ o1, bf16* __restrict__ o2,
    bf16* __restrict__ o3, bf16* __restrict__ o4, bf16* __restrict__ o5) {
  const float* in;
  bf16* out;
  int n4;
  switch (blockIdx.y) {
    case 0: in = i0; out = o0; n4 = (S_SEQ * E_DIM) / 4; break;
    case 1: in = i1; out = o1; n4 = (S_SEQ * E_DIM) / 4; break;
    case 2: in = i2; out = o2; n4 = (S_SEQ * E_DIM) / 4; break;
    case 3: in = i3; out = o3; n4 = (D_DIM * E_DIM) / 4; break;
    case 4: in = i4; out = o4; n4 = (D_DIM * E_DIM) / 4; break;
    default: in = i5; out = o5; n4 = (D_DIM * E_DIM) / 4; break;
  }
  int i = blockIdx.x * 256 + threadIdx.x;
  if (i < n4) {
    float4 v = reinterpret_cast<const float4*>(in)[i];
    bf16x4 o;
    o[0] = (bf16)v.x; o[1] = (bf16)v.y; o[2] = (bf16)v.z; o[3] = (bf16)v.w;
    *reinterpret_cast<bf16x4*>(out + 4 * (size_t)i) = o;
  }
}

// ---------------------------------------------------------------------------
// async global->LDS 16B (wave-uniform lds base + lane*16 scatter)
// ---------------------------------------------------------------------------
__device__ __forceinline__ void async_copy16(const bf16* g, bf16* l) {
  __builtin_amdgcn_global_load_lds(
      (const __attribute__((address_space(1))) void*)g,
      (__attribute__((address_space(3))) void*)l, 16, 0, 0);
}

// ---------------------------------------------------------------------------
// XCD-aware tile remaps. Both bijective; 4(m) x 2(n) XCD grid.
// ---------------------------------------------------------------------------
__device__ __forceinline__ void xcd_remap32(int id, int nt, int& m, int& n) {
  int xcd = id & 7;
  int lid = id >> 3;
  m = (xcd & 3) * 8 + (lid & 7);
  n = (xcd >> 2) * (nt >> 1) + (lid >> 3);
}
__device__ __forceinline__ void xcd_remap16(int id, int nt, int& m, int& n) {
  int xcd = id & 7;
  int lid = id >> 3;
  m = (xcd & 3) * 4 + (lid & 3);
  n = (xcd >> 2) * (nt >> 1) + (lid >> 2);
}

// stage one half-tile (128 rows x 64 cols bf16 = 16 KB), 512 threads:
// 2 global_load_lds_dwordx4 per thread. k-chunks XOR-permuted via the
// pre-swizzled GLOBAL source (slot = kchunk ^ (row&7)); LDS dest linear.
__device__ __forceinline__ void stage_half(const bf16* __restrict__ G, int ld,
                                           int grow0, int k0, bf16* lds,
                                           int wave, int lane) {
#pragma unroll
  for (int s = 0; s < 2; ++s) {
    int c = (wave * 2 + s) * 64 + lane;
    int row = c >> 3;
    int kc = (c & 7) ^ (row & 7);
    const bf16* g = G + (size_t)(grow0 + row) * ld + k0 + kc * 8;
    async_copy16(g, lds + (size_t)(wave * 2 + s) * 512);
  }
}

#define BARRIER __builtin_amdgcn_s_barrier()
#define LGKM0 asm volatile("s_waitcnt lgkmcnt(0)" ::: "memory")
#define VMCNT2 asm volatile("s_waitcnt vmcnt(2)" ::: "memory")
#define VMCNT0 asm volatile("s_waitcnt vmcnt(0)" ::: "memory")

// ===========================================================================
// BODY A (proj, control): single-buffer 128x128, BK=64, 4 waves (2x2), wave
// tile 64x64. 32 KB LDS -> ~2.6 blocks/CU; implicit multi-block overlap.
// Measured 97-106 us / MfmaUtil 45-49% across sessions.
// ===========================================================================
template <int EPI>
__device__ __forceinline__ void gemm_body_sb(
    const bf16* __restrict__ A, int lda,
    const bf16* __restrict__ B, int ldb,
    void* __restrict__ C, int ldc,
    const float* __restrict__ aux, float scale, int K, int mBase, int nBase) {
  __shared__ __align__(16) bf16 Als[128 * 64];   // 16 KB
  __shared__ __align__(16) bf16 Bls[128 * 64];   // 16 KB

  const int tid  = threadIdx.x;
  const int wave = tid >> 6;
  const int lane = tid & 63;
  const int quad = lane >> 4;
  const int lrow = lane & 15;
  const int wRow = (wave >> 1) * 64;
  const int wCol = (wave & 1) * 64;

  f32x4 acc[4][4];
#pragma unroll
  for (int i = 0; i < 4; ++i)
#pragma unroll
    for (int j = 0; j < 4; ++j) {
      f32x4 z = {0.f, 0.f, 0.f, 0.f};
      acc[i][j] = z;
    }

  for (int k0 = 0; k0 < K; k0 += 64) {
#pragma unroll
    for (int c = 0; c < 4; ++c) {
      int chunk = c * 256 + tid;
      int row = chunk >> 3;
      int kc = (chunk & 7) ^ (row & 7);
      const bf16* g = A + (size_t)(mBase + row) * lda + k0 + kc * 8;
      async_copy16(g, Als + (size_t)(c * 256 + wave * 64) * 8);
    }
#pragma unroll
    for (int c = 0; c < 4; ++c) {
      int chunk = c * 256 + tid;
      int row = chunk >> 3;
      int kc = (chunk & 7) ^ (row & 7);
      const bf16* g = B + (size_t)(nBase + row) * ldb + k0 + kc * 8;
      async_copy16(g, Bls + (size_t)(c * 256 + wave * 64) * 8);
    }
    __syncthreads();

#pragma unroll
    for (int kk = 0; kk < 2; ++kk) {
      bf16x8 af[4], bfr[4];
#pragma unroll
      for (int i = 0; i < 4; ++i) {
        int r = wRow + i * 16 + lrow;
        int slot = (kk * 4 + quad) ^ (r & 7);
        af[i] = *(const bf16x8*)(Als + (size_t)r * 64 + slot * 8);
      }
#pragma unroll
      for (int j = 0; j < 4; ++j) {
        int r = wCol + j * 16 + lrow;
        int slot = (kk * 4 + quad) ^ (r & 7);
        bfr[j] = *(const bf16x8*)(Bls + (size_t)r * 64 + slot * 8);
      }
#pragma unroll
      for (int i = 0; i < 4; ++i)
#pragma unroll
        for (int j = 0; j < 4; ++j)
          acc[i][j] = __builtin_amdgcn_mfma_f32_16x16x32_bf16(af[i], bfr[j], acc[i][j], 0, 0, 0);
    }
    __syncthreads();
  }

#pragma unroll
  for (int j = 0; j < 4; ++j) {
    const int cn = nBase + wCol + j * 16 + lrow;
    float bj = 0.f;
    if (EPI == 0) bj = aux[cn];
#pragma unroll
    for (int i = 0; i < 4; ++i) {
      const int rbase = mBase + wRow + i * 16 + quad * 4;
#pragma unroll
      for (int r = 0; r < 4; ++r) {
        if (EPI == 0)
          ((bf16*)C)[(size_t)(rbase + r) * ldc + cn] = (bf16)(acc[i][j][r] + bj);
      }
    }
  }
}

// ===========================================================================
// QK8 (r12): template-geometry 8-phase counted-vmcnt GEMM. 256x256 tile,
// BK=64, 512 threads = 8 waves (2M x 4N), wave tile 128x64 -> LDS-read/MFMA
// cycle ratio 0.93 (compute-bound; the prerequisite r2/r3's 64x64-wave-tile
// ports violated at ratio 1.24). 128 KB LDS dbuf -> 1 block/CU, 8 waves.
// Per iter = 2 K-tiles (e->buf0, o->buf1), 8 phases; each phase stages ONE
// 16KB half-tile (2 gloads) and runs 16 MFMA (one C-quadrant x K=64).
// Halves per tile: A.lo,A.hi,B.lo,B.hi. Stage slots: o.{Ahi,Blo,Bhi} in
// ph1-3, ne.{Alo,Ahi,Blo,Bhi} in ph4-7, no.Alo in ph8 (o.Alo staged at prev
// ph8). vmcnt(2) at ph4 (tile-o's 4 halves landed; ne.Alo in flight) and
// ph8 (ne landed; no.Alo in flight) — never drains to 0 in the main loop.
// Overwrite-safety: each half staged strictly after its buffer's last
// ds_read phase + intervening barrier (hand-verified, see quadrant order).
// Quadrant order per tile: (i0,j0),(i0,j1),(i1,j1),(i1,j0) — A-half and b0
// cached across the zigzag. Epilogue: bf16 exp(acc*scale) + psum partials.
// ===========================================================================
__global__ __launch_bounds__(512, 2) void qk8_gemm(
    const bf16* __restrict__ A, const bf16* __restrict__ B,
    bf16* __restrict__ E, float scale, float* __restrict__ psum) {
  __shared__ __align__(16) bf16 Als[2][256 * 64];  // 64 KB
  __shared__ __align__(16) bf16 Bls[2][256 * 64];  // 64 KB

  int m, n;
  xcd_remap16(blockIdx.x, 16, m, n);
  const int mBase = m * 256, nBase = n * 256;
  const int lda = D_DIM, ldb = D_DIM, ldc = S_SEQ;
  const int K = D_DIM;

  const int tid  = threadIdx.x;
  const int wave = tid >> 6;   // 0..7
  const int lane = tid & 63;
  const int quad = lane >> 4;
  const int lrow = lane & 15;
  const int wm = wave >> 2;    // 0..1
  const int wn = wave & 3;     // 0..3
  const int wRow = wm * 128;
  const int wCol = wn * 64;

  f32x4 acc[8][4];
#pragma unroll
  for (int i = 0; i < 8; ++i)
#pragma unroll
    for (int j = 0; j < 4; ++j) {
      f32x4 z = {0.f, 0.f, 0.f, 0.f};
      acc[i][j] = z;
    }

  bf16x8 aR[4][2], b0[2][2], b1[2][2];

  // read A i-quadrant QI (4 frags x 2 kk) from buf
  auto rdA = [&](int buf, int QI) {
#pragma unroll
    for (int i = 0; i < 4; ++i)
#pragma unroll
      for (int kk = 0; kk < 2; ++kk) {
        int r = wRow + QI * 64 + i * 16 + lrow;
        int slot = (kk * 4 + quad) ^ (r & 7);
        aR[i][kk] = *(const bf16x8*)(&Als[buf][(size_t)r * 64 + slot * 8]);
      }
  };
  // read B j-pair JP (2 frags x 2 kk) from buf into dst
  auto rdB = [&](int buf, int JP, bf16x8 (&dst)[2][2]) {
#pragma unroll
    for (int j = 0; j < 2; ++j)
#pragma unroll
      for (int kk = 0; kk < 2; ++kk) {
        int r = wCol + (JP * 2 + j) * 16 + lrow;
        int slot = (kk * 4 + quad) ^ (r & 7);
        dst[j][kk] = *(const bf16x8*)(&Bls[buf][(size_t)r * 64 + slot * 8]);
      }
  };
  // 16-MFMA C-quadrant (QI, JP) x K=64
  auto mma = [&](int QI, int JP, bf16x8 (&bb)[2][2]) {
    __builtin_amdgcn_s_setprio(1);
#pragma unroll
    for (int i = 0; i < 4; ++i)
#pragma unroll
      for (int j = 0; j < 2; ++j)
#pragma unroll
        for (int kk = 0; kk < 2; ++kk)
          acc[QI * 4 + i][JP * 2 + j] = __builtin_amdgcn_mfma_f32_16x16x32_bf16(
              aR[i][kk], bb[j][kk], acc[QI * 4 + i][JP * 2 + j], 0, 0, 0);
    __builtin_amdgcn_s_setprio(0);
  };

  // prologue: tile0 x4 halves + tile1.A.lo (10 loads/thr); vmcnt(2) = tile0 in
  stage_half(A, lda, mBase,       0, &Als[0][0],        wave, lane);
  stage_half(A, lda, mBase + 128, 0, &Als[0][128 * 64], wave, lane);
  stage_half(B, ldb, nBase,       0, &Bls[0][0],        wave, lane);
  stage_half(B, ldb, nBase + 128, 0, &Bls[0][128 * 64], wave, lane);
  stage_half(A, lda, mBase,      64, &Als[1][0],        wave, lane);
  VMCNT2;
  BARRIER;

  const int NI = K >> 7;  // 16 iters (2 K-tiles each)
#pragma unroll 1
  for (int i = 0; i < NI; ++i) {
    const bool nl = (i + 1 < NI);
    const int kb = i * 128;
    // ph1 (e: q(i0,j0))
    stage_half(A, lda, mBase + 128, kb + 64, &Als[1][128 * 64], wave, lane);  // o.Ahi
    rdA(0, 0); rdB(0, 0, b0);
    BARRIER; LGKM0; mma(0, 0, b0); BARRIER;
    // ph2 (e: q(i0,j1))
    stage_half(B, ldb, nBase,       kb + 64, &Bls[1][0],        wave, lane);  // o.Blo
    rdB(0, 1, b1);
    BARRIER; LGKM0; mma(0, 1, b1); BARRIER;
    // ph3 (e: q(i1,j1))
    stage_half(B, ldb, nBase + 128, kb + 64, &Bls[1][128 * 64], wave, lane);  // o.Bhi
    rdA(0, 1);
    BARRIER; LGKM0; mma(1, 1, b1); BARRIER;
    // ph4 (e: q(i1,j0)) — cached aR(i1), b0; tile-o landed check
    if (nl) {
      stage_half(A, lda, mBase, kb + 128, &Als[0][0], wave, lane);            // ne.Alo
      VMCNT2;
    } else {
      VMCNT0;
    }
    BARRIER; mma(1, 0, b0); BARRIER;
    // ph5 (o: q(i0,j0))
    if (nl) stage_half(A, lda, mBase + 128, kb + 128, &Als[0][128 * 64], wave, lane);  // ne.Ahi
    rdA(1, 0); rdB(1, 0, b0);
    BARRIER; LGKM0; mma(0, 0, b0); BARRIER;
    // ph6 (o: q(i0,j1))
    if (nl) stage_half(B, ldb, nBase,       kb + 128, &Bls[0][0],        wave, lane);  // ne.Blo
    rdB(1, 1, b1);
    BARRIER; LGKM0; mma(0, 1, b1); BARRIER;
    // ph7 (o: q(i1,j1))
    if (nl) stage_half(B, ldb, nBase + 128, kb + 128, &Bls[0][128 * 64], wave, lane);  // ne.Bhi
    rdA(1, 1);
    BARRIER; LGKM0; mma(1, 1, b1); BARRIER;
    // ph8 (o: q(i1,j0)) — tile-ne landed check
    if (nl) {
      stage_half(A, lda, mBase, kb + 192, &Als[1][0], wave, lane);            // no.Alo
      VMCNT2;
    }
    BARRIER; mma(1, 0, b0); BARRIER;
  }

  // epilogue: bf16 exp(acc*scale) + per-row partial sums (verified layout)
  float sp[8][4];
#pragma unroll
  for (int i = 0; i < 8; ++i)
#pragma unroll
    for (int r = 0; r < 4; ++r) sp[i][r] = 0.f;
#pragma unroll
  for (int j = 0; j < 4; ++j) {
    const int cn = nBase + wCol + j * 16 + lrow;
#pragma unroll
    for (int i = 0; i < 8; ++i) {
      const int rbase = mBase + wRow + i * 16 + quad * 4;
#pragma unroll
      for (int r = 0; r < 4; ++r) {
        bf16 eb = (bf16)__expf(acc[i][j][r] * scale);
        E[(size_t)(rbase + r) * ldc + cn] = eb;
        sp[i][r] += (float)eb;
      }
    }
  }
#pragma unroll
  for (int i = 0; i < 8; ++i)
#pragma unroll
    for (int r = 0; r < 4; ++r) {
#pragma unroll
      for (int off = 1; off < 16; off <<= 1)
        sp[i][r] += __shfl_xor(sp[i][r], off, 64);
    }
  if (lrow == 0) {
    const int col64 = (nBase + wCol) >> 6;  // 0..63, unique per (block-n, wn)
#pragma unroll
    for (int i = 0; i < 8; ++i) {
      const int rbase = mBase + wRow + i * 16 + quad * 4;
#pragma unroll
      for (int r = 0; r < 4; ++r)
        psum[(size_t)(rbase + r) * 64 + col64] = sp[i][r];
    }
  }
}

// ===========================================================================
// BODY B (pv): 4-phase counted-vmcnt 256x128, BK=64, 8 waves (4x2), wave
// tile 64x64. 96 KB LDS, 8 waves/CU. Verified r3/r6/r7/r11 (pv < 97us).
// ===========================================================================
#define RD_A(buf, IP)                                                         \
  _Pragma("unroll") for (int ii = 0; ii < 2; ++ii)                            \
  _Pragma("unroll") for (int kk = 0; kk < 2; ++kk)                            \
      aR[ii][kk] = *(const bf16x8*)(&Als[buf][(size_t)(wRow + ((IP)*2 + ii) * 16 + lrow) * 64 + slotk[kk] * 8]);

#define RD_B(buf, JP, dst)                                                    \
  _Pragma("unroll") for (int jj = 0; jj < 2; ++jj)                            \
  _Pragma("unroll") for (int kk = 0; kk < 2; ++kk)                            \
      dst[jj][kk] = *(const bf16x8*)(&Bls[buf][(size_t)(wCol + ((JP)*2 + jj) * 16 + lrow) * 64 + slotk[kk] * 8]);

#define MMA16(IP)                                                              \
  __builtin_amdgcn_s_setprio(1);                                               \
  _Pragma("unroll") for (int jj = 0; jj < 2; ++jj)                             \
  _Pragma("unroll") for (int ii = 0; ii < 2; ++ii)                             \
  _Pragma("unroll") for (int kk = 0; kk < 2; ++kk)                             \
      acc[(IP)*2 + ii][jj] = __builtin_amdgcn_mfma_f32_16x16x32_bf16(          \
          aR[ii][kk], b0[jj][kk], acc[(IP)*2 + ii][jj], 0, 0, 0);              \
  _Pragma("unroll") for (int jj = 0; jj < 2; ++jj)                             \
  _Pragma("unroll") for (int ii = 0; ii < 2; ++ii)                             \
  _Pragma("unroll") for (int kk = 0; kk < 2; ++kk)                             \
      acc[(IP)*2 + ii][2 + jj] = __builtin_amdgcn_mfma_f32_16x16x32_bf16(      \
          aR[ii][kk], b1[jj][kk], acc[(IP)*2 + ii][2 + jj], 0, 0, 0);          \
  __builtin_amdgcn_s_setprio(0)

template <int EPI>
__device__ __forceinline__ void gemm_body_4ph(
    const bf16* __restrict__ A, int lda,
    const bf16* __restrict__ B, int ldb,
    void* __restrict__ C, int ldc,
    const float* __restrict__ aux, float scale, int K, int mBase, int nBase) {
  __shared__ __align__(16) bf16 Als[2][256 * 64];  // 64 KB
  __shared__ __align__(16) bf16 Bls[2][128 * 64];  // 32 KB

  const int tid  = threadIdx.x;
  const int wave = tid >> 6;
  const int lane = tid & 63;
  const int quad = lane >> 4;
  const int lrow = lane & 15;
  const int wRow = (wave >> 1) * 64;
  const int wCol = (wave & 1) * 64;
  const int slotk[2] = {quad ^ (lrow & 7), (4 + quad) ^ (lrow & 7)};

  f32x4 acc[4][4];
#pragma unroll
  for (int i = 0; i < 4; ++i)
#pragma unroll
    for (int j = 0; j < 4; ++j) {
      f32x4 z = {0.f, 0.f, 0.f, 0.f};
      acc[i][j] = z;
    }

  bf16x8 aR[2][2], b0[2][2], b1[2][2];

  stage_half(B, ldb, nBase, 0, &Bls[0][0], wave, lane);
  stage_half(A, lda, mBase, 0, &Als[0][0], wave, lane);
  stage_half(A, lda, mBase + 128, 0, &Als[0][128 * 64], wave, lane);
  stage_half(B, ldb, nBase, 64, &Bls[1][0], wave, lane);
  VMCNT2;
  BARRIER;

  const int NI = K >> 7;
#pragma unroll 1
  for (int i = 0; i < NI; ++i) {
    const bool nl = (i + 1 < NI);
    const int kb = i * 128;
    RD_A(0, 0);
    RD_B(0, 0, b0);
    RD_B(0, 1, b1);
    stage_half(A, lda, mBase, kb + 64, &Als[1][0], wave, lane);
    stage_half(A, lda, mBase + 128, kb + 64, &Als[1][128 * 64], wave, lane);
    BARRIER; LGKM0; MMA16(0); BARRIER;
    RD_A(0, 1);
    if (nl) {
      stage_half(B, ldb, nBase, kb + 128, &Bls[0][0], wave, lane);
      VMCNT2;
    } else {
      VMCNT0;
    }
    BARRIER; LGKM0; MMA16(1); BARRIER;
    RD_A(1, 0);
    RD_B(1, 0, b0);
    RD_B(1, 1, b1);
    if (nl) {
      stage_half(A, lda, mBase, kb + 128, &Als[0][0], wave, lane);
      stage_half(A, lda, mBase + 128, kb + 128, &Als[0][128 * 64], wave, lane);
    }
    BARRIER; LGKM0; MMA16(0); BARRIER;
    RD_A(1, 1);
    if (nl) {
      stage_half(B, ldb, nBase, kb + 192, &Bls[1][0], wave, lane);
      VMCNT2;
    }
    BARRIER; LGKM0; MMA16(1); BARRIER;
  }

  float rinv[4][4];
#pragma unroll
  for (int i = 0; i < 4; ++i)
#pragma unroll
    for (int r = 0; r < 4; ++r)
      rinv[i][r] = aux[mBase + wRow + i * 16 + quad * 4 + r];
#pragma unroll
  for (int j = 0; j < 4; ++j) {
    const int cn = nBase + wCol + j * 16 + lrow;
#pragma unroll
    for (int i = 0; i < 4; ++i) {
      const int rbase = mBase + wRow + i * 16 + quad * 4;
#pragma unroll
      for (int r = 0; r < 4; ++r)
        ((float*)C)[(size_t)(rbase + r) * ldc + cn] = acc[i][j][r] * rinv[i][r];
    }
  }
}

// PV: out = (E @ vT^T) * inv[row], fp32 out. BODY B (8 waves), 256 blocks.
__global__ __launch_bounds__(512, 2) void pv_gemm(
    const bf16* __restrict__ E, const bf16* __restrict__ vT,
    float* __restrict__ out, const float* __restrict__ inv) {
  int m, n;
  xcd_remap16(blockIdx.x, 16, m, n);
  gemm_body_4ph<2>(E, S_SEQ, vT, S_SEQ, (void*)out, D_DIM, inv, 0.f, S_SEQ,
                   m * 256, n * 128);
}

// merged projections: BODY A (control), mt=32, nt=16 -> 512 blocks/slice.
__global__ __launch_bounds__(256, 2) void proj_gemm(
    const bf16* __restrict__ xk, const bf16* __restrict__ xq,
    const bf16* __restrict__ xv,
    const bf16* __restrict__ Wk, const bf16* __restrict__ Wq,
    const bf16* __restrict__ Wv,
    const float* __restrict__ bk, const float* __restrict__ bq,
    const float* __restrict__ bv,
    bf16* __restrict__ ok, bf16* __restrict__ oq, bf16* __restrict__ ov) {
  const bf16 *A, *W;
  const float* b;
  bf16* o;
  switch (blockIdx.z) {
    case 0: A = xk; W = Wk; b = bk; o = ok; break;
    case 1: A = xq; W = Wq; b = bq; o = oq; break;
    default: A = xv; W = Wv; b = bv; o = ov; break;
  }
  int m, n;
  xcd_remap32(blockIdx.x, 16, m, n);
  gemm_body_sb<0>(A, E_DIM, W, E_DIM, (void*)o, D_DIM, b, 0.f, E_DIM,
                  m * 128, n * 128);
}

// ---------------------------------------------------------------------------
// bf16 transpose: in[S,D] -> out[D,S], 64x64 tiles via LDS (r6-verified)
// ---------------------------------------------------------------------------
__global__ __launch_bounds__(256) void transpose_bf16(
    const bf16* __restrict__ in, bf16* __restrict__ out) {
  __shared__ bf16 tile[64][66];
  const int t = threadIdx.x;
  const int c0 = blockIdx.x * 64;
  const int r0 = blockIdx.y * 64;
  const int col = t & 63;
  const int r4 = t >> 6;
#pragma unroll
  for (int i = 0; i < 16; ++i) {
    int rr = i * 4 + r4;
    tile[rr][col] = in[(size_t)(r0 + rr) * D_DIM + c0 + col];
  }
  __syncthreads();
#pragma unroll
  for (int i = 0; i < 16; ++i) {
    int rr = i * 4 + r4;
    out[(size_t)(c0 + rr) * S_SEQ + r0 + col] = tile[col][rr];
  }
}

// ---------------------------------------------------------------------------
// rowsum2: inv[r] = 1 / sum(psum[r, 0..63]). One row per thread; 1 MB read.
// ---------------------------------------------------------------------------
__global__ __launch_bounds__(256) void rowsum2(
    const float* __restrict__ psum, float* __restrict__ inv) {
  const int r = blockIdx.x * 256 + threadIdx.x;
  const f32x4* p = (const f32x4*)(psum + (size_t)r * 64);
  float s = 0.f;
#pragma unroll
  for (int i = 0; i < 16; ++i) {
    f32x4 v = p[i];
    s += v[0] + v[1] + v[2] + v[3];
  }
  inv[r] = 1.0f / s;
}

// ---------------------------------------------------------------------------
// launcher
// ---------------------------------------------------------------------------
extern "C" void kernel_launch(void* const* d_in, const int* in_sizes, int n_in,
                              void* d_out, int out_size, void* d_ws, size_t ws_size,
                              hipStream_t stream) {
  const float* key   = (const float*)d_in[0];
  const float* value = (const float*)d_in[1];
  const float* query = (const float*)d_in[2];
  const float* Wk = (const float*)d_in[3];
  const float* bk = (const float*)d_in[4];
  const float* Wq = (const float*)d_in[5];
  const float* bq = (const float*)d_in[6];
  const float* Wv = (const float*)d_in[7];
  const float* bv = (const float*)d_in[8];

  const size_t MB = 1ull << 20;
  char* ws = (char*)d_ws;
  bf16* key_bf   = (bf16*)(ws + 0 * MB);
  bf16* value_bf = (bf16*)(ws + 16 * MB);
  bf16* query_bf = (bf16*)(ws + 32 * MB);
  bf16* Wk_bf    = (bf16*)(ws + 48 * MB);
  bf16* Wq_bf    = (bf16*)(ws + 56 * MB);
  bf16* Wv_bf    = (bf16*)(ws + 64 * MB);
  bf16* k_bf     = (bf16*)(ws + 72 * MB);
  bf16* q_bf     = (bf16*)(ws + 88 * MB);
  bf16* v_bf     = (bf16*)(ws + 104 * MB);
  bf16* vT_bf    = (bf16*)(ws + 120 * MB);
  bf16* E        = (bf16*)(ws + 0 * MB);
  float* psum    = (float*)(ws + 34 * MB);
  float* inv     = (float*)(ws + 35 * MB);

  dim3 blk(256);
  dim3 blk512(512);

  // 1. all six casts
  cast6<<<dim3(8192, 6), blk, 0, stream>>>(
      key, value, query, Wk, Wq, Wv,
      key_bf, value_bf, query_bf, Wk_bf, Wq_bf, Wv_bf);

  // 2. projections (BODY A): 512 blocks/slice
  proj_gemm<<<dim3(512, 1, 3), blk, 0, stream>>>(
      key_bf, query_bf, value_bf, Wk_bf, Wq_bf, Wv_bf, bk, bq, bv,
      k_bf, q_bf, v_bf);

  // 3. v^T for the PV GEMM (separate dispatch; qk8's 128KB LDS would
  //    serialize merged transpose blocks anyway)
  transpose_bf16<<<dim3(D_DIM / 64, S_SEQ / 64), blk, 0, stream>>>(v_bf, vT_bf);

  // 4. E = exp(q@k^T*scale) + psum (8-phase 256^2): 16m x 16n = 256 blocks
  const float scale = 0.022097086912079608f;  // 1/sqrt(2048)
  qk8_gemm<<<dim3(256), blk512, 0, stream>>>(q_bf, k_bf, E, scale, psum);

  // 5. inv[r] = 1/rowsum (1 MB of partials)
  rowsum2<<<dim3(16), blk, 0, stream>>>(psum, inv);

  // 6. out = (E @ v) * inv[row] (BODY B, 8 waves): 256 blocks
  pv_gemm<<<dim3(256), blk512, 0, stream>>>(E, vT_bf, (float*)d_out, inv);
}